// Round 12
// baseline (172.698 us; speedup 1.0000x reference)
//
#include <hip/hip_runtime.h>
#include <hip/hip_bf16.h>
#include <cstdint>
#include <cstddef>

typedef __bf16 bf16;
typedef bf16 bf16x8 __attribute__((ext_vector_type(8)));
typedef float floatx4 __attribute__((ext_vector_type(4)));
typedef int intx8 __attribute__((ext_vector_type(8)));
typedef int intx4 __attribute__((ext_vector_type(4)));

#define DEVI __device__ __forceinline__

#define C_  512
#define HW_ 4096
#define B_  2
#define M_  8192   // B_*HW_
#define TK  64

// Journal: R14 WIN swizzle. R16 WIN counted-vmcnt dbuf. R17/R20 ~176.
// R18/R19 3-buf dead. R21 LDS-staged P stores regressed. R22 fused attn
// regressed hard (TLP >> locality/pipelining on this problem). R23 WIN
// (176->167): l fused into pv via ones-column MFMA; qk rowsum+atomics gone.
// R24: qk was 1 block/CU (96KB dbuf) -> zero inter-block overlap; its 25K
// cy/round is only ~4.4K MFMA. Trade dbuf for TLP: single-buffer 256x128
// (48KB) -> 2 blocks/CU; per-iter stage-drain now covered by the co-resident
// block (R0/R13/R18/R22 lesson: TLP beats in-block pipelining here).

DEVI floatx4 mfma16(bf16x8 a, bf16x8 b, floatx4 c) {
  return __builtin_amdgcn_mfma_f32_16x16x32_bf16(a, b, c, 0, 0, 0);
}

// fp8 e4m3 MX-scaled MFMA with unit scales (E8M0 127 = 2^0): plain fp8 GEMM
// at 2x bf16 rate, K=128 per instruction.
DEVI floatx4 mfma_fp8(intx8 a, intx8 b, floatx4 c) {
  return __builtin_amdgcn_mfma_scale_f32_16x16x128_f8f6f4(a, b, c, 0, 0,
                                                          0, 127, 0, 127);
}

// Direct HBM->LDS DMA, 16B per lane. LDS dest is wave-uniform base + lane*16.
DEVI void gload16(const void* g, void* lds) {
  using gp = const __attribute__((address_space(1))) unsigned int*;
  using lp = __attribute__((address_space(3))) unsigned int*;
  __builtin_amdgcn_global_load_lds(
      reinterpret_cast<gp>(reinterpret_cast<uintptr_t>(g)),
      reinterpret_cast<lp>((unsigned int)(uintptr_t)lds), 16, 0, 0);
}

template <int N> DEVI void wait_vmcnt() {
  if constexpr (N == 0)       asm volatile("s_waitcnt vmcnt(0)" ::: "memory");
  else if constexpr (N == 6)  asm volatile("s_waitcnt vmcnt(6)" ::: "memory");
  else if constexpr (N == 8)  asm volatile("s_waitcnt vmcnt(8)" ::: "memory");
  else static_assert(N == 0, "unsupported vmcnt literal");
}

// float -> fp8 e4m3 byte (OCP on gfx950)
DEVI uint32_t f32_to_fp8(float x) {
  return (uint32_t)__builtin_amdgcn_cvt_pk_fp8_f32(x, x, 0, false) & 0xffu;
}
DEVI int pack4_fp8(float a, float b, float c, float d) {
  int pk = __builtin_amdgcn_cvt_pk_fp8_f32(a, b, 0, false);
  return __builtin_amdgcn_cvt_pk_fp8_f32(c, d, pk, true);
}

// ---- GroupNorm partial sums (512 blocks) -----------------------------------
__global__ __launch_bounds__(256) void gn_part(const float* __restrict__ x,
                                               float* __restrict__ pp) {
  int blk = blockIdx.x;              // 0..511
  int t = threadIdx.x;
  int batch = blk >> 8;
  int pix0 = (blk & 255) * 16;
  int c4 = (t & 127) << 2;           // channel quad (one group)
  int ph = t >> 7;                   // 0/1 pixel phase
  const float* px = x + (size_t)batch * HW_ * C_ + (size_t)(pix0 + ph) * C_ + c4;
  float s1 = 0.f, s2 = 0.f;
#pragma unroll
  for (int i = 0; i < 8; i++) {
    float4 v = *reinterpret_cast<const float4*>(px + (size_t)i * 2 * C_);
    s1 += v.x + v.y + v.z + v.w;
    s2 += v.x * v.x + v.y * v.y + v.z * v.z + v.w * v.w;
  }
  __shared__ float l1[256], l2[256];
  l1[t] = s1; l2[t] = s2;
  __syncthreads();
  if (t < 32) {                      // group g = t: slots g*4+j (+128)
    float a = 0.f, b2 = 0.f;
#pragma unroll
    for (int j = 0; j < 4; j++) {
      a  += l1[t * 4 + j] + l1[t * 4 + j + 128];
      b2 += l2[t * 4 + j] + l2[t * 4 + j + 128];
    }
    pp[blk * 32 + t] = a;
    pp[512 * 32 + blk * 32 + t] = b2;
  }
}

// ---- Fused: blocks 0..63 = gn_finish; blocks 64..1087 = weight transpose ---
__global__ __launch_bounds__(256) void finish_wtrans(
    const float* __restrict__ pp, float* __restrict__ stats,
    const float* __restrict__ wq, const float* __restrict__ wk,
    const float* __restrict__ wv, const float* __restrict__ wp,
    uint8_t* __restrict__ w8, bf16* __restrict__ wtp) {
  int t = threadIdx.x;
  if (blockIdx.x < 64) {
    int bg = blockIdx.x;             // b*32+g
    int b = bg >> 5, g = bg & 31;
    float s1 = pp[(b * 256 + t) * 32 + g];
    float s2 = pp[512 * 32 + (b * 256 + t) * 32 + g];
    for (int off = 32; off; off >>= 1) {
      s1 += __shfl_down(s1, off);
      s2 += __shfl_down(s2, off);
    }
    __shared__ float r1[4], r2[4];
    int wid = t >> 6;
    if ((t & 63) == 0) { r1[wid] = s1; r2[wid] = s2; }
    __syncthreads();
    if (t == 0) {
      s1 = r1[0] + r1[1] + r1[2] + r1[3];
      s2 = r2[0] + r2[1] + r2[2] + r2[3];
      float inv = 1.0f / (HW_ * 16);
      float mean = s1 * inv;
      float var  = s2 * inv - mean * mean;
      stats[bg]      = mean;
      stats[64 + bg] = rsqrtf(var + 1e-5f);
    }
    return;
  }
  int id = blockIdx.x - 64;          // 0..1023: (z, 16x16 tile grid of 32x32)
  int z = id >> 8;
  int k0 = ((id >> 4) & 15) * 32, n0 = (id & 15) * 32;
  const float* w = (z == 0) ? wq : (z == 1) ? wk : (z == 2) ? wv : wp;
  __shared__ float tt[32][33];
  int r = t >> 5, cc = t & 31;
  for (int i = 0; i < 4; i++) {
    int rr = r + i * 8;
    tt[rr][cc] = w[(size_t)(k0 + rr) * C_ + n0 + cc];
  }
  __syncthreads();
  if (z < 3) {
    uint8_t* dst = w8 + (size_t)z * C_ * C_;
    for (int i = 0; i < 4; i++) {
      int rr = r + i * 8;
      dst[(size_t)(n0 + rr) * C_ + k0 + cc] = (uint8_t)f32_to_fp8(tt[cc][rr]);
    }
  } else {
    for (int i = 0; i < 4; i++) {
      int rr = r + i * 8;
      wtp[(size_t)(n0 + rr) * C_ + k0 + cc] = (bf16)tt[cc][rr];
    }
  }
}

// ---------------- Apply GN -> h8 fp8 (M_ x C_) ------------------------------
__global__ __launch_bounds__(256) void gn_apply(const float* __restrict__ x,
                                                const float* __restrict__ gamma,
                                                const float* __restrict__ beta,
                                                const float* __restrict__ stats,
                                                uint8_t* __restrict__ h8) {
  int idx = blockIdx.x * 256 + threadIdx.x;    // 4 elems each
  int m  = idx >> 7;
  int c4 = (idx & 127) << 2;
  int b = m >> 12;
  int g = c4 >> 4;
  float mean = stats[(b << 5) + g];
  float rs   = stats[64 + (b << 5) + g];
  const float4 xv = *reinterpret_cast<const float4*>(x + (size_t)m * C_ + c4);
  const float4 gv = *reinterpret_cast<const float4*>(gamma + c4);
  const float4 bv = *reinterpret_cast<const float4*>(beta + c4);
  int pk = pack4_fp8((xv.x - mean) * rs * gv.x + bv.x,
                     (xv.y - mean) * rs * gv.y + bv.y,
                     (xv.z - mean) * rs * gv.z + bv.z,
                     (xv.w - mean) * rs * gv.w + bv.w);
  *reinterpret_cast<int*>(h8 + (size_t)m * C_ + c4) = pk;
}

// ---- bf16 GEMM mainloop: counted-vmcnt dbuf (R16) + swizzled LDS (R14) -----
template <int BM, int BN, int MT, int NT>
DEVI void gemm_main(const bf16* __restrict__ A, int lda,
                    const bf16* __restrict__ Bt, int ldb,
                    int K, floatx4 (&acc)[MT][NT]) {
  constexpr int WCOLS = BN / (NT * 16);
  constexpr int NLD = BM / 32 + BN / 32;
  static_assert(NLD == 6 || NLD == 8, "vmcnt literal supports 6/8");
  __shared__ __align__(16) bf16 As[2][BM * TK];
  __shared__ __align__(16) bf16 Bs[2][BN * TK];
  int tid = threadIdx.x;
  int w = tid >> 6, lane = tid & 63;
  int wrow = w / WCOLS, wcol = w % WCOLS;
  int col = lane & 15, quad = lane >> 4;
#pragma unroll
  for (int mt = 0; mt < MT; mt++)
#pragma unroll
    for (int nt = 0; nt < NT; nt++)
      acc[mt][nt] = floatx4{0.f, 0.f, 0.f, 0.f};

  auto stage = [&](int k0, bf16* as, bf16* bs) {
#pragma unroll
    for (int i = 0; i < BM / 32; i++) {
      int id = tid + i * 256;                // row=id>>3, word=id&7
      int r = id >> 3, wd = id & 7;
      gload16(A + (size_t)r * lda + k0 + ((wd ^ (r & 7)) << 3), as + id * 8);
    }
#pragma unroll
    for (int i = 0; i < BN / 32; i++) {
      int id = tid + i * 256;
      int r = id >> 3, wd = id & 7;
      gload16(Bt + (size_t)r * ldb + k0 + ((wd ^ (r & 7)) << 3), bs + id * 8);
    }
  };
  auto compute = [&](const bf16* sa, const bf16* sb) {
#pragma unroll
    for (int kk = 0; kk < 2; kk++) {
      bf16x8 af[MT], bfr[NT];
#pragma unroll
      for (int mt = 0; mt < MT; mt++) {
        int rA = wrow * MT * 16 + mt * 16 + col;
        af[mt] = *reinterpret_cast<const bf16x8*>(
            sa + rA * TK + (((kk * 4 + quad) ^ (rA & 7)) << 3));
      }
#pragma unroll
      for (int nt = 0; nt < NT; nt++) {
        int rB = wcol * NT * 16 + nt * 16 + col;
        bfr[nt] = *reinterpret_cast<const bf16x8*>(
            sb + rB * TK + (((kk * 4 + quad) ^ (rB & 7)) << 3));
      }
#pragma unroll
      for (int mt = 0; mt < MT; mt++)
#pragma unroll
        for (int nt = 0; nt < NT; nt++)
          acc[mt][nt] = mfma16(af[mt], bfr[nt], acc[mt][nt]);
    }
  };

  bf16 *s0a = &As[0][0], *s0b = &Bs[0][0];
  bf16 *s1a = &As[1][0], *s1b = &Bs[1][0];
  stage(0, s0a, s0b);
  int nIter = K / TK;
  for (int t = 0; t < nIter - 1; t++) {
    stage((t + 1) * TK, s1a, s1b);                 // NLD loads in flight
    wait_vmcnt<NLD>();                             // tile t landed
    asm volatile("s_barrier" ::: "memory");
    compute(s0a, s0b);
    asm volatile("s_waitcnt lgkmcnt(0)" ::: "memory");
    asm volatile("s_barrier" ::: "memory");        // reads done -> overwrite ok
    bf16* tp;
    tp = s0a; s0a = s1a; s1a = tp;
    tp = s0b; s0b = s1b; s1b = tp;
  }
  wait_vmcnt<0>();
  asm volatile("s_barrier" ::: "memory");
  compute(s0a, s0b);
}

// ---- fp8 MX GEMM mainloop: counted-vmcnt dbuf, THREADS-generic -------------
// TK=128 bytes/row. A-frag 32B/lane (k=quad*32+j) = two swizzled 16B reads.
// WITH_L: also accumulate row-sums of A via ones-column MFMA (l = A x 1).
template <int BM, int BN, int MT, int NT, int THREADS, bool WITH_L>
DEVI void gemm_fp8(const uint8_t* __restrict__ A, int lda,
                   const uint8_t* __restrict__ Bt, int ldb,
                   int K, floatx4 (&acc)[MT][NT], floatx4 (&accl)[MT]) {
  constexpr int WCOLS = BN / (NT * 16);
  constexpr int RPP = THREADS / 8;               // tile rows staged per pass
  constexpr int NLD = (BM + BN) / RPP;           // gloads/thread/stage
  static_assert(NLD == 6 || NLD == 8, "vmcnt literal supports 6/8");
  static_assert(BM % RPP == 0 && BN % RPP == 0, "stage pass mismatch");
  __shared__ __align__(16) uint8_t As[2][BM * 128];
  __shared__ __align__(16) uint8_t Bs[2][BN * 128];
  int tid = threadIdx.x;
  int w = tid >> 6, lane = tid & 63;
  int wrow = w / WCOLS, wcol = w % WCOLS;
  int col = lane & 15, quad = lane >> 4;
  const intx8 ones = {0x38383838, 0x38383838, 0x38383838, 0x38383838,
                      0x38383838, 0x38383838, 0x38383838, 0x38383838};
#pragma unroll
  for (int mt = 0; mt < MT; mt++) {
#pragma unroll
    for (int nt = 0; nt < NT; nt++)
      acc[mt][nt] = floatx4{0.f, 0.f, 0.f, 0.f};
    accl[mt] = floatx4{0.f, 0.f, 0.f, 0.f};
  }

  auto stage = [&](int k0, uint8_t* as, uint8_t* bs) {
#pragma unroll
    for (int i = 0; i < BM / RPP; i++) {     // row = id>>3 (8 lanes x 16B)
      int id = tid + i * THREADS;
      int r = id >> 3, wd = id & 7;
      gload16(A + (size_t)r * lda + k0 + ((wd ^ (r & 7)) << 4), as + id * 16);
    }
#pragma unroll
    for (int i = 0; i < BN / RPP; i++) {
      int id = tid + i * THREADS;
      int r = id >> 3, wd = id & 7;
      gload16(Bt + (size_t)r * ldb + k0 + ((wd ^ (r & 7)) << 4), bs + id * 16);
    }
  };
  auto compute = [&](const uint8_t* sa, const uint8_t* sb) {
    intx8 af[MT], bfr[NT];
#pragma unroll
    for (int mt = 0; mt < MT; mt++) {
      int rA = wrow * MT * 16 + mt * 16 + col;
      const uint8_t* rowp = sa + (size_t)rA * 128;
      intx4 lo = *reinterpret_cast<const intx4*>(
          rowp + (((2 * quad) ^ (rA & 7)) << 4));
      intx4 hi = *reinterpret_cast<const intx4*>(
          rowp + (((2 * quad + 1) ^ (rA & 7)) << 4));
      af[mt] = __builtin_shufflevector(lo, hi, 0, 1, 2, 3, 4, 5, 6, 7);
    }
#pragma unroll
    for (int nt = 0; nt < NT; nt++) {
      int rB = wcol * NT * 16 + nt * 16 + col;
      const uint8_t* rowp = sb + (size_t)rB * 128;
      intx4 lo = *reinterpret_cast<const intx4*>(
          rowp + (((2 * quad) ^ (rB & 7)) << 4));
      intx4 hi = *reinterpret_cast<const intx4*>(
          rowp + (((2 * quad + 1) ^ (rB & 7)) << 4));
      bfr[nt] = __builtin_shufflevector(lo, hi, 0, 1, 2, 3, 4, 5, 6, 7);
    }
#pragma unroll
    for (int mt = 0; mt < MT; mt++) {
#pragma unroll
      for (int nt = 0; nt < NT; nt++)
        acc[mt][nt] = mfma_fp8(af[mt], bfr[nt], acc[mt][nt]);
      if constexpr (WITH_L)
        accl[mt] = mfma_fp8(af[mt], ones, accl[mt]);
    }
  };

  uint8_t *s0a = &As[0][0], *s0b = &Bs[0][0];
  uint8_t *s1a = &As[1][0], *s1b = &Bs[1][0];
  stage(0, s0a, s0b);
  int nIter = K >> 7;
  for (int t = 0; t < nIter - 1; t++) {
    stage((t + 1) << 7, s1a, s1b);                 // NLD loads in flight
    wait_vmcnt<NLD>();                             // tile t landed
    asm volatile("s_barrier" ::: "memory");
    compute(s0a, s0b);
    asm volatile("s_waitcnt lgkmcnt(0)" ::: "memory");
    asm volatile("s_barrier" ::: "memory");        // reads done -> overwrite ok
    uint8_t* tp;
    tp = s0a; s0a = s1a; s1a = tp;
    tp = s0b; s0b = s1b; s1b = tp;
  }
  wait_vmcnt<0>();
  asm volatile("s_barrier" ::: "memory");
  compute(s0a, s0b);
}

// ---- fp8 MX GEMM mainloop: SINGLE buffer (R24, for qk @ 2 blocks/CU) -------
// stage -> syncthreads (drains vmcnt) -> compute -> syncthreads. The exposed
// per-iter drain is covered by the co-resident block (TLP).
template <int BM, int BN, int MT, int NT, int THREADS>
DEVI void gemm_fp8_sb(const uint8_t* __restrict__ A, int lda,
                      const uint8_t* __restrict__ Bt, int ldb,
                      int K, floatx4 (&acc)[MT][NT]) {
  constexpr int WCOLS = BN / (NT * 16);
  constexpr int RPP = THREADS / 8;               // tile rows staged per pass
  __shared__ __align__(16) uint8_t As[BM * 128];
  __shared__ __align__(16) uint8_t Bs[BN * 128];
  int tid = threadIdx.x;
  int w = tid >> 6, lane = tid & 63;
  int wrow = w / WCOLS, wcol = w % WCOLS;
  int col = lane & 15, quad = lane >> 4;
#pragma unroll
  for (int mt = 0; mt < MT; mt++)
#pragma unroll
    for (int nt = 0; nt < NT; nt++)
      acc[mt][nt] = floatx4{0.f, 0.f, 0.f, 0.f};
  for (int k0 = 0; k0 < K; k0 += 128) {
    __syncthreads();                           // prior reads done
#pragma unroll
    for (int i = 0; i < BM / RPP; i++) {       // row = id>>3 (8 lanes x 16B)
      int id = tid + i * THREADS;
      int r = id >> 3, wd = id & 7;
      gload16(A + (size_t)r * lda + k0 + ((wd ^ (r & 7)) << 4), As + id * 16);
    }
#pragma unroll
    for (int i = 0; i < BN / RPP; i++) {
      int id = tid + i * THREADS;
      int r = id >> 3, wd = id & 7;
      gload16(Bt + (size_t)r * ldb + k0 + ((wd ^ (r & 7)) << 4), Bs + id * 16);
    }
    __syncthreads();                           // drains vmcnt -> LDS valid
    intx8 af[MT], bfr[NT];
#pragma unroll
    for (int mt = 0; mt < MT; mt++) {
      int rA = wrow * MT * 16 + mt * 16 + col;
      const uint8_t* rowp = As + (size_t)rA * 128;
      intx4 lo = *reinterpret_cast<const intx4*>(
          rowp + (((2 * quad) ^ (rA & 7)) << 4));
      intx4 hi = *reinterpret_cast<const intx4*>(
          rowp + (((2 * quad + 1) ^ (rA & 7)) << 4));
      af[mt] = __builtin_shufflevector(lo, hi, 0, 1, 2, 3, 4, 5, 6, 7);
    }
#pragma unroll
    for (int nt = 0; nt < NT; nt++) {
      int rB = wcol * NT * 16 + nt * 16 + col;
      const uint8_t* rowp = Bs + (size_t)rB * 128;
      intx4 lo = *reinterpret_cast<const intx4*>(
          rowp + (((2 * quad) ^ (rB & 7)) << 4));
      intx4 hi = *reinterpret_cast<const intx4*>(
          rowp + (((2 * quad + 1) ^ (rB & 7)) << 4));
      bfr[nt] = __builtin_shufflevector(lo, hi, 0, 1, 2, 3, 4, 5, 6, 7);
    }
#pragma unroll
    for (int mt = 0; mt < MT; mt++)
#pragma unroll
      for (int nt = 0; nt < NT; nt++)
        acc[mt][nt] = mfma_fp8(af[mt], bfr[nt], acc[mt][nt]);
  }
}

// ---------------- QKV fp8 GEMM (h8 x w8): q8, k8, vt8 -----------------------
// 128x128 tile, 64x64 wave tile -> grid (64, 4, 3) = 768 blocks. K=512.
__global__ __launch_bounds__(256) void gemm_qkv(const uint8_t* __restrict__ h8,
                                                const uint8_t* __restrict__ w8,
                                                const float* __restrict__ bq,
                                                const float* __restrict__ bk,
                                                const float* __restrict__ bv,
                                                uint8_t* __restrict__ q8,
                                                uint8_t* __restrict__ k8,
                                                uint8_t* __restrict__ vt8) {
  int z = blockIdx.z;
  int m0 = blockIdx.x * 128, n0 = blockIdx.y * 128;
  floatx4 acc[4][4];
  floatx4 accl[4];
  gemm_fp8<128, 128, 4, 4, 256, false>(h8 + (size_t)m0 * C_, C_,
                                       w8 + (size_t)z * C_ * C_ + (size_t)n0 * C_,
                                       C_, C_, acc, accl);
  int tid = threadIdx.x, w = tid >> 6, lane = tid & 63;
  int wrow = w >> 1, wcol = w & 1;           // WCOLS=2
  int col = lane & 15, quad = lane >> 4;
  const float* bias = (z == 0) ? bq : (z == 1) ? bk : bv;
  if (z < 2) {
    uint8_t* out = (z == 0) ? q8 : k8;
#pragma unroll
    for (int mt = 0; mt < 4; mt++)
#pragma unroll
      for (int nt = 0; nt < 4; nt++) {
        int n = n0 + wcol * 64 + nt * 16 + col;
        float bb = bias[n];
#pragma unroll
        for (int r = 0; r < 4; r++) {
          int m = m0 + wrow * 64 + mt * 16 + quad * 4 + r;
          out[(size_t)m * C_ + n] = (uint8_t)f32_to_fp8(acc[mt][nt][r] + bb);
        }
      }
  } else {
    // vt8[b][c][s] = fp8(v[b*4096+s][c]); 4 consecutive s -> packed int store
#pragma unroll
    for (int mt = 0; mt < 4; mt++)
#pragma unroll
      for (int nt = 0; nt < 4; nt++) {
        int n = n0 + wcol * 64 + nt * 16 + col;
        float bb = bias[n];
        int mbase = m0 + wrow * 64 + mt * 16 + quad * 4;
        int b = mbase >> 12;
        int s = mbase & 4095;
        int pk = pack4_fp8(acc[mt][nt][0] + bb, acc[mt][nt][1] + bb,
                           acc[mt][nt][2] + bb, acc[mt][nt][3] + bb);
        *reinterpret_cast<int*>(vt8 + ((size_t)b * C_ + n) * HW_ + s) = pk;
      }
  }
}

// ---------------- QK^T fp8 GEMM -> P8 = fp8(exp(S*scale)) -------------------
// 256x128 tile, 512 threads, SINGLE 48KB buffer -> 2 blocks/CU (R24).
// grid (16, 32, B); bijective XCD swizzle (q8 2MB L2-resident per XCD).
// K=512 -> 4 iters. No rowsum (l computed in pv via ones-MFMA).
__global__ __launch_bounds__(512) void gemm_qk(const uint8_t* __restrict__ q8,
                                               const uint8_t* __restrict__ k8,
                                               uint8_t* __restrict__ P8) {
  int b = blockIdx.z;
  int fid = blockIdx.y * 16 + blockIdx.x;    // 0..511
  int nid = (fid & 7) * 64 + (fid >> 3);     // XCD-contiguous chunks of 64
  int m0 = (nid & 15) * 256, n0 = (nid >> 4) * 128;
  floatx4 acc[4][4];
  gemm_fp8_sb<256, 128, 4, 4, 512>(q8 + ((size_t)b * HW_ + m0) * C_, C_,
                                   k8 + ((size_t)b * HW_ + n0) * C_, C_, C_, acc);
  int tid = threadIdx.x, w = tid >> 6, lane = tid & 63;
  int wrow = w >> 1, wcol = w & 1;           // WCOLS=2; wrow 0..3
  int col = lane & 15, quad = lane >> 4;
  const float sl2e = 0.044194173824159216f * 1.4426950408889634f; // scale*log2e
  uint8_t* Pb = P8 + (size_t)b * HW_ * HW_;
#pragma unroll
  for (int mt = 0; mt < 4; mt++) {
#pragma unroll
    for (int nt = 0; nt < 4; nt++) {
      int n = n0 + wcol * 64 + nt * 16 + col;
      float p0 = exp2f(acc[mt][nt][0] * sl2e);
      float p1 = exp2f(acc[mt][nt][1] * sl2e);
      float p2 = exp2f(acc[mt][nt][2] * sl2e);
      float p3 = exp2f(acc[mt][nt][3] * sl2e);
      int pk = pack4_fp8(p0, p1, p2, p3);
      size_t base = (size_t)(m0 + wrow * 64 + mt * 16 + quad * 4) * HW_ + n;
      Pb[base]           = (uint8_t)pk;
      Pb[base + HW_]     = (uint8_t)((unsigned)pk >> 8);
      Pb[base + 2 * HW_] = (uint8_t)((unsigned)pk >> 16);
      Pb[base + 3 * HW_] = (uint8_t)((unsigned)pk >> 24);
    }
  }
}

// ---------------- PV fp8 GEMM: O = P8 * V8^T, l = P8 x 1, o = O/l -----------
// 128x64 tile, dbuf -> grid (32, 8, B) = 512 blocks (2/CU). K=4096 -> 32
// iters. XCD swizzle: XCD x owns 4 P8 m-panels x all 8 n-tiles -> P8 (2MB)
// + vt8 (2MB) L2-resident. l via ones-MFMA: accl[mt][r] lands on exactly
// the lane that writes row m = m0+w*32+mt*16+quad*4+r.
__global__ __launch_bounds__(256) void gemm_pv(const uint8_t* __restrict__ P8,
                                               const uint8_t* __restrict__ vt8,
                                               bf16* __restrict__ o) {
  int b = blockIdx.z;
  int fid = blockIdx.y * 32 + blockIdx.x;    // 0..255
  int xcd = fid & 7, i = fid >> 3;           // i in 0..31
  int m0 = (xcd * 4 + (i & 3)) * 128;        // 4 m-panels per XCD
  int n0 = (i >> 2) * 64;                    // all 8 n-tiles per XCD
  floatx4 acc[2][4];
  floatx4 accl[2];
  gemm_fp8<128, 64, 2, 4, 256, true>(P8 + (size_t)b * HW_ * HW_ + (size_t)m0 * HW_,
                                     HW_, vt8 + ((size_t)b * C_ + n0) * HW_, HW_,
                                     HW_, acc, accl);
  int tid = threadIdx.x, w = tid >> 6, lane = tid & 63;
  int col = lane & 15, quad = lane >> 4;     // WCOLS=1 -> wave rows w*32
  bf16* ob = o + (size_t)b * HW_ * C_;
#pragma unroll
  for (int mt = 0; mt < 2; mt++)
#pragma unroll
    for (int r = 0; r < 4; r++) {
      int m = m0 + w * 32 + mt * 16 + quad * 4 + r;
      float inv = 1.0f / accl[mt][r];
#pragma unroll
      for (int nt = 0; nt < 4; nt++) {
        int n = n0 + nt * 16 + col;
        ob[(size_t)m * C_ + n] = (bf16)(acc[mt][nt][r] * inv);
      }
    }
}

// ---------------- Proj GEMM + residual: out = x + o*wp + bp (fp32) ----------
// 128x64 tile, dbuf (R17 config) -> grid (64, 8) = 512 blocks (2/CU).
__global__ __launch_bounds__(256) void gemm_proj(const bf16* __restrict__ o,
                                                 const bf16* __restrict__ wtp,
                                                 const float* __restrict__ bp,
                                                 const float* __restrict__ x,
                                                 float* __restrict__ out) {
  int m0 = blockIdx.x * 128, n0 = blockIdx.y * 64;
  floatx4 acc[2][4];
  gemm_main<128, 64, 2, 4>(o + (size_t)m0 * C_, C_, wtp + (size_t)n0 * C_, C_, C_, acc);
  int tid = threadIdx.x, w = tid >> 6, lane = tid & 63;
  int col = lane & 15, quad = lane >> 4;     // WCOLS=1 -> wave rows w*32
#pragma unroll
  for (int mt = 0; mt < 2; mt++)
#pragma unroll
    for (int nt = 0; nt < 4; nt++) {
      int n = n0 + nt * 16 + col;
      float bb = bp[n];
#pragma unroll
      for (int r = 0; r < 4; r++) {
        int m = m0 + w * 32 + mt * 16 + quad * 4 + r;
        out[(size_t)m * C_ + n] = x[(size_t)m * C_ + n] + acc[mt][nt][r] + bb;
      }
    }
}

// ---------------- launch -----------------------------------------------------
extern "C" void kernel_launch(void* const* d_in, const int* in_sizes, int n_in,
                              void* d_out, int out_size, void* d_ws, size_t ws_size,
                              hipStream_t stream) {
  const float* x     = (const float*)d_in[0];
  const float* gamma = (const float*)d_in[1];
  const float* beta  = (const float*)d_in[2];
  const float* wq    = (const float*)d_in[3];
  const float* bq    = (const float*)d_in[4];
  const float* wk    = (const float*)d_in[5];
  const float* bk    = (const float*)d_in[6];
  const float* wv    = (const float*)d_in[7];
  const float* bv    = (const float*)d_in[8];
  const float* wp    = (const float*)d_in[9];
  const float* bp    = (const float*)d_in[10];
  float* out = (float*)d_out;

  char* w8s = (char*)d_ws;
  float* stats = (float*)(w8s);                      // 512 B
  float* pp    = (float*)(w8s + 393216u);            // 128 KB
  uint8_t* w8  = (uint8_t*)(w8s + (1u << 20));       // 768 KB (fp8 wq/wk/wv ^T)
  bf16* wtp    = (bf16*)(w8s + (2u << 20));          // 512 KB (bf16 wp^T)
  uint8_t* h8  = (uint8_t*)(w8s + (4u << 20));       // 4 MB
  bf16* o      = (bf16*)(w8s + (8u << 20));          // 8 MB
  uint8_t* q8  = (uint8_t*)(w8s + (16u << 20));      // 4 MB
  uint8_t* k8  = (uint8_t*)(w8s + (20u << 20));      // 4 MB
  uint8_t* vt8 = (uint8_t*)(w8s + (24u << 20));      // 4 MB
  uint8_t* P8  = (uint8_t*)(w8s + (28u << 20));      // 32 MB -> 60 MB total

  gn_part<<<512, 256, 0, stream>>>(x, pp);
  finish_wtrans<<<1088, 256, 0, stream>>>(pp, stats, wq, wk, wv, wp, w8, wtp);
  gn_apply<<<4096, 256, 0, stream>>>(x, gamma, beta, stats, h8);
  gemm_qkv<<<dim3(M_ / 128, C_ / 128, 3), 256, 0, stream>>>(h8, w8, bq, bk, bv, q8, k8, vt8);
  gemm_qk<<<dim3(HW_ / 256, HW_ / 128, B_), 512, 0, stream>>>(q8, k8, P8);
  gemm_pv<<<dim3(HW_ / 128, C_ / 64, B_), 256, 0, stream>>>(P8, vt8, o);
  gemm_proj<<<dim3(M_ / 128, C_ / 64, 1), 256, 0, stream>>>(o, wtp, bp, x, out);
}

// Round 13
// 161.834 us; speedup vs baseline: 1.0671x; 1.0671x over previous
//
#include <hip/hip_runtime.h>
#include <hip/hip_bf16.h>
#include <cstdint>
#include <cstddef>

typedef __bf16 bf16;
typedef bf16 bf16x8 __attribute__((ext_vector_type(8)));
typedef float floatx4 __attribute__((ext_vector_type(4)));
typedef int intx8 __attribute__((ext_vector_type(8)));
typedef int intx4 __attribute__((ext_vector_type(4)));

#define DEVI __device__ __forceinline__

#define C_  512
#define HW_ 4096
#define B_  2
#define M_  8192   // B_*HW_
#define TK  64

// Journal: R14 WIN swizzle. R16 WIN counted-vmcnt dbuf. R23 WIN (167.1):
// l fused into pv via ones-column MFMA. R18/R19 3-buf dead. R21 LDS-staged
// P stores dead. R22 fused attn dead. R24 single-buf qk @2blk dead (172.7):
// co-resident vmcnt(0) drains contend on the same L2 path.
// R25: last untested qk cell: 128x128 dbuf (2 blocks/CU, counted vmcnt,
// R17 XCD swizzle) WITHOUT rowsum epilogue (R23's removal). Combines the
// proven dbuf + TLP + free epilogue. Everything else = R23 winner verbatim.

DEVI floatx4 mfma16(bf16x8 a, bf16x8 b, floatx4 c) {
  return __builtin_amdgcn_mfma_f32_16x16x32_bf16(a, b, c, 0, 0, 0);
}

// fp8 e4m3 MX-scaled MFMA with unit scales (E8M0 127 = 2^0): plain fp8 GEMM
// at 2x bf16 rate, K=128 per instruction.
DEVI floatx4 mfma_fp8(intx8 a, intx8 b, floatx4 c) {
  return __builtin_amdgcn_mfma_scale_f32_16x16x128_f8f6f4(a, b, c, 0, 0,
                                                          0, 127, 0, 127);
}

// Direct HBM->LDS DMA, 16B per lane. LDS dest is wave-uniform base + lane*16.
DEVI void gload16(const void* g, void* lds) {
  using gp = const __attribute__((address_space(1))) unsigned int*;
  using lp = __attribute__((address_space(3))) unsigned int*;
  __builtin_amdgcn_global_load_lds(
      reinterpret_cast<gp>(reinterpret_cast<uintptr_t>(g)),
      reinterpret_cast<lp>((unsigned int)(uintptr_t)lds), 16, 0, 0);
}

template <int N> DEVI void wait_vmcnt() {
  if constexpr (N == 0)       asm volatile("s_waitcnt vmcnt(0)" ::: "memory");
  else if constexpr (N == 6)  asm volatile("s_waitcnt vmcnt(6)" ::: "memory");
  else if constexpr (N == 8)  asm volatile("s_waitcnt vmcnt(8)" ::: "memory");
  else static_assert(N == 0, "unsupported vmcnt literal");
}

// float -> fp8 e4m3 byte (OCP on gfx950)
DEVI uint32_t f32_to_fp8(float x) {
  return (uint32_t)__builtin_amdgcn_cvt_pk_fp8_f32(x, x, 0, false) & 0xffu;
}
DEVI int pack4_fp8(float a, float b, float c, float d) {
  int pk = __builtin_amdgcn_cvt_pk_fp8_f32(a, b, 0, false);
  return __builtin_amdgcn_cvt_pk_fp8_f32(c, d, pk, true);
}

// ---- GroupNorm partial sums (512 blocks) -----------------------------------
__global__ __launch_bounds__(256) void gn_part(const float* __restrict__ x,
                                               float* __restrict__ pp) {
  int blk = blockIdx.x;              // 0..511
  int t = threadIdx.x;
  int batch = blk >> 8;
  int pix0 = (blk & 255) * 16;
  int c4 = (t & 127) << 2;           // channel quad (one group)
  int ph = t >> 7;                   // 0/1 pixel phase
  const float* px = x + (size_t)batch * HW_ * C_ + (size_t)(pix0 + ph) * C_ + c4;
  float s1 = 0.f, s2 = 0.f;
#pragma unroll
  for (int i = 0; i < 8; i++) {
    float4 v = *reinterpret_cast<const float4*>(px + (size_t)i * 2 * C_);
    s1 += v.x + v.y + v.z + v.w;
    s2 += v.x * v.x + v.y * v.y + v.z * v.z + v.w * v.w;
  }
  __shared__ float l1[256], l2[256];
  l1[t] = s1; l2[t] = s2;
  __syncthreads();
  if (t < 32) {                      // group g = t: slots g*4+j (+128)
    float a = 0.f, b2 = 0.f;
#pragma unroll
    for (int j = 0; j < 4; j++) {
      a  += l1[t * 4 + j] + l1[t * 4 + j + 128];
      b2 += l2[t * 4 + j] + l2[t * 4 + j + 128];
    }
    pp[blk * 32 + t] = a;
    pp[512 * 32 + blk * 32 + t] = b2;
  }
}

// ---- Fused: blocks 0..63 = gn_finish; blocks 64..1087 = weight transpose ---
__global__ __launch_bounds__(256) void finish_wtrans(
    const float* __restrict__ pp, float* __restrict__ stats,
    const float* __restrict__ wq, const float* __restrict__ wk,
    const float* __restrict__ wv, const float* __restrict__ wp,
    uint8_t* __restrict__ w8, bf16* __restrict__ wtp) {
  int t = threadIdx.x;
  if (blockIdx.x < 64) {
    int bg = blockIdx.x;             // b*32+g
    int b = bg >> 5, g = bg & 31;
    float s1 = pp[(b * 256 + t) * 32 + g];
    float s2 = pp[512 * 32 + (b * 256 + t) * 32 + g];
    for (int off = 32; off; off >>= 1) {
      s1 += __shfl_down(s1, off);
      s2 += __shfl_down(s2, off);
    }
    __shared__ float r1[4], r2[4];
    int wid = t >> 6;
    if ((t & 63) == 0) { r1[wid] = s1; r2[wid] = s2; }
    __syncthreads();
    if (t == 0) {
      s1 = r1[0] + r1[1] + r1[2] + r1[3];
      s2 = r2[0] + r2[1] + r2[2] + r2[3];
      float inv = 1.0f / (HW_ * 16);
      float mean = s1 * inv;
      float var  = s2 * inv - mean * mean;
      stats[bg]      = mean;
      stats[64 + bg] = rsqrtf(var + 1e-5f);
    }
    return;
  }
  int id = blockIdx.x - 64;          // 0..1023: (z, 16x16 tile grid of 32x32)
  int z = id >> 8;
  int k0 = ((id >> 4) & 15) * 32, n0 = (id & 15) * 32;
  const float* w = (z == 0) ? wq : (z == 1) ? wk : (z == 2) ? wv : wp;
  __shared__ float tt[32][33];
  int r = t >> 5, cc = t & 31;
  for (int i = 0; i < 4; i++) {
    int rr = r + i * 8;
    tt[rr][cc] = w[(size_t)(k0 + rr) * C_ + n0 + cc];
  }
  __syncthreads();
  if (z < 3) {
    uint8_t* dst = w8 + (size_t)z * C_ * C_;
    for (int i = 0; i < 4; i++) {
      int rr = r + i * 8;
      dst[(size_t)(n0 + rr) * C_ + k0 + cc] = (uint8_t)f32_to_fp8(tt[cc][rr]);
    }
  } else {
    for (int i = 0; i < 4; i++) {
      int rr = r + i * 8;
      wtp[(size_t)(n0 + rr) * C_ + k0 + cc] = (bf16)tt[cc][rr];
    }
  }
}

// ---------------- Apply GN -> h8 fp8 (M_ x C_) ------------------------------
__global__ __launch_bounds__(256) void gn_apply(const float* __restrict__ x,
                                                const float* __restrict__ gamma,
                                                const float* __restrict__ beta,
                                                const float* __restrict__ stats,
                                                uint8_t* __restrict__ h8) {
  int idx = blockIdx.x * 256 + threadIdx.x;    // 4 elems each
  int m  = idx >> 7;
  int c4 = (idx & 127) << 2;
  int b = m >> 12;
  int g = c4 >> 4;
  float mean = stats[(b << 5) + g];
  float rs   = stats[64 + (b << 5) + g];
  const float4 xv = *reinterpret_cast<const float4*>(x + (size_t)m * C_ + c4);
  const float4 gv = *reinterpret_cast<const float4*>(gamma + c4);
  const float4 bv = *reinterpret_cast<const float4*>(beta + c4);
  int pk = pack4_fp8((xv.x - mean) * rs * gv.x + bv.x,
                     (xv.y - mean) * rs * gv.y + bv.y,
                     (xv.z - mean) * rs * gv.z + bv.z,
                     (xv.w - mean) * rs * gv.w + bv.w);
  *reinterpret_cast<int*>(h8 + (size_t)m * C_ + c4) = pk;
}

// ---- bf16 GEMM mainloop: counted-vmcnt dbuf (R16) + swizzled LDS (R14) -----
template <int BM, int BN, int MT, int NT>
DEVI void gemm_main(const bf16* __restrict__ A, int lda,
                    const bf16* __restrict__ Bt, int ldb,
                    int K, floatx4 (&acc)[MT][NT]) {
  constexpr int WCOLS = BN / (NT * 16);
  constexpr int NLD = BM / 32 + BN / 32;
  static_assert(NLD == 6 || NLD == 8, "vmcnt literal supports 6/8");
  __shared__ __align__(16) bf16 As[2][BM * TK];
  __shared__ __align__(16) bf16 Bs[2][BN * TK];
  int tid = threadIdx.x;
  int w = tid >> 6, lane = tid & 63;
  int wrow = w / WCOLS, wcol = w % WCOLS;
  int col = lane & 15, quad = lane >> 4;
#pragma unroll
  for (int mt = 0; mt < MT; mt++)
#pragma unroll
    for (int nt = 0; nt < NT; nt++)
      acc[mt][nt] = floatx4{0.f, 0.f, 0.f, 0.f};

  auto stage = [&](int k0, bf16* as, bf16* bs) {
#pragma unroll
    for (int i = 0; i < BM / 32; i++) {
      int id = tid + i * 256;                // row=id>>3, word=id&7
      int r = id >> 3, wd = id & 7;
      gload16(A + (size_t)r * lda + k0 + ((wd ^ (r & 7)) << 3), as + id * 8);
    }
#pragma unroll
    for (int i = 0; i < BN / 32; i++) {
      int id = tid + i * 256;
      int r = id >> 3, wd = id & 7;
      gload16(Bt + (size_t)r * ldb + k0 + ((wd ^ (r & 7)) << 3), bs + id * 8);
    }
  };
  auto compute = [&](const bf16* sa, const bf16* sb) {
#pragma unroll
    for (int kk = 0; kk < 2; kk++) {
      bf16x8 af[MT], bfr[NT];
#pragma unroll
      for (int mt = 0; mt < MT; mt++) {
        int rA = wrow * MT * 16 + mt * 16 + col;
        af[mt] = *reinterpret_cast<const bf16x8*>(
            sa + rA * TK + (((kk * 4 + quad) ^ (rA & 7)) << 3));
      }
#pragma unroll
      for (int nt = 0; nt < NT; nt++) {
        int rB = wcol * NT * 16 + nt * 16 + col;
        bfr[nt] = *reinterpret_cast<const bf16x8*>(
            sb + rB * TK + (((kk * 4 + quad) ^ (rB & 7)) << 3));
      }
#pragma unroll
      for (int mt = 0; mt < MT; mt++)
#pragma unroll
        for (int nt = 0; nt < NT; nt++)
          acc[mt][nt] = mfma16(af[mt], bfr[nt], acc[mt][nt]);
    }
  };

  bf16 *s0a = &As[0][0], *s0b = &Bs[0][0];
  bf16 *s1a = &As[1][0], *s1b = &Bs[1][0];
  stage(0, s0a, s0b);
  int nIter = K / TK;
  for (int t = 0; t < nIter - 1; t++) {
    stage((t + 1) * TK, s1a, s1b);                 // NLD loads in flight
    wait_vmcnt<NLD>();                             // tile t landed
    asm volatile("s_barrier" ::: "memory");
    compute(s0a, s0b);
    asm volatile("s_waitcnt lgkmcnt(0)" ::: "memory");
    asm volatile("s_barrier" ::: "memory");        // reads done -> overwrite ok
    bf16* tp;
    tp = s0a; s0a = s1a; s1a = tp;
    tp = s0b; s0b = s1b; s1b = tp;
  }
  wait_vmcnt<0>();
  asm volatile("s_barrier" ::: "memory");
  compute(s0a, s0b);
}

// ---- fp8 MX GEMM mainloop: counted-vmcnt dbuf, THREADS-generic -------------
// TK=128 bytes/row. A-frag 32B/lane (k=quad*32+j) = two swizzled 16B reads.
// WITH_L: also accumulate row-sums of A via ones-column MFMA (l = A x 1).
template <int BM, int BN, int MT, int NT, int THREADS, bool WITH_L>
DEVI void gemm_fp8(const uint8_t* __restrict__ A, int lda,
                   const uint8_t* __restrict__ Bt, int ldb,
                   int K, floatx4 (&acc)[MT][NT], floatx4 (&accl)[MT]) {
  constexpr int WCOLS = BN / (NT * 16);
  constexpr int RPP = THREADS / 8;               // tile rows staged per pass
  constexpr int NLD = (BM + BN) / RPP;           // gloads/thread/stage
  static_assert(NLD == 6 || NLD == 8, "vmcnt literal supports 6/8");
  static_assert(BM % RPP == 0 && BN % RPP == 0, "stage pass mismatch");
  __shared__ __align__(16) uint8_t As[2][BM * 128];
  __shared__ __align__(16) uint8_t Bs[2][BN * 128];
  int tid = threadIdx.x;
  int w = tid >> 6, lane = tid & 63;
  int wrow = w / WCOLS, wcol = w % WCOLS;
  int col = lane & 15, quad = lane >> 4;
  const intx8 ones = {0x38383838, 0x38383838, 0x38383838, 0x38383838,
                      0x38383838, 0x38383838, 0x38383838, 0x38383838};
#pragma unroll
  for (int mt = 0; mt < MT; mt++) {
#pragma unroll
    for (int nt = 0; nt < NT; nt++)
      acc[mt][nt] = floatx4{0.f, 0.f, 0.f, 0.f};
    accl[mt] = floatx4{0.f, 0.f, 0.f, 0.f};
  }

  auto stage = [&](int k0, uint8_t* as, uint8_t* bs) {
#pragma unroll
    for (int i = 0; i < BM / RPP; i++) {     // row = id>>3 (8 lanes x 16B)
      int id = tid + i * THREADS;
      int r = id >> 3, wd = id & 7;
      gload16(A + (size_t)r * lda + k0 + ((wd ^ (r & 7)) << 4), as + id * 16);
    }
#pragma unroll
    for (int i = 0; i < BN / RPP; i++) {
      int id = tid + i * THREADS;
      int r = id >> 3, wd = id & 7;
      gload16(Bt + (size_t)r * ldb + k0 + ((wd ^ (r & 7)) << 4), bs + id * 16);
    }
  };
  auto compute = [&](const uint8_t* sa, const uint8_t* sb) {
    intx8 af[MT], bfr[NT];
#pragma unroll
    for (int mt = 0; mt < MT; mt++) {
      int rA = wrow * MT * 16 + mt * 16 + col;
      const uint8_t* rowp = sa + (size_t)rA * 128;
      intx4 lo = *reinterpret_cast<const intx4*>(
          rowp + (((2 * quad) ^ (rA & 7)) << 4));
      intx4 hi = *reinterpret_cast<const intx4*>(
          rowp + (((2 * quad + 1) ^ (rA & 7)) << 4));
      af[mt] = __builtin_shufflevector(lo, hi, 0, 1, 2, 3, 4, 5, 6, 7);
    }
#pragma unroll
    for (int nt = 0; nt < NT; nt++) {
      int rB = wcol * NT * 16 + nt * 16 + col;
      const uint8_t* rowp = sb + (size_t)rB * 128;
      intx4 lo = *reinterpret_cast<const intx4*>(
          rowp + (((2 * quad) ^ (rB & 7)) << 4));
      intx4 hi = *reinterpret_cast<const intx4*>(
          rowp + (((2 * quad + 1) ^ (rB & 7)) << 4));
      bfr[nt] = __builtin_shufflevector(lo, hi, 0, 1, 2, 3, 4, 5, 6, 7);
    }
#pragma unroll
    for (int mt = 0; mt < MT; mt++) {
#pragma unroll
      for (int nt = 0; nt < NT; nt++)
        acc[mt][nt] = mfma_fp8(af[mt], bfr[nt], acc[mt][nt]);
      if constexpr (WITH_L)
        accl[mt] = mfma_fp8(af[mt], ones, accl[mt]);
    }
  };

  uint8_t *s0a = &As[0][0], *s0b = &Bs[0][0];
  uint8_t *s1a = &As[1][0], *s1b = &Bs[1][0];
  stage(0, s0a, s0b);
  int nIter = K >> 7;
  for (int t = 0; t < nIter - 1; t++) {
    stage((t + 1) << 7, s1a, s1b);                 // NLD loads in flight
    wait_vmcnt<NLD>();                             // tile t landed
    asm volatile("s_barrier" ::: "memory");
    compute(s0a, s0b);
    asm volatile("s_waitcnt lgkmcnt(0)" ::: "memory");
    asm volatile("s_barrier" ::: "memory");        // reads done -> overwrite ok
    uint8_t* tp;
    tp = s0a; s0a = s1a; s1a = tp;
    tp = s0b; s0b = s1b; s1b = tp;
  }
  wait_vmcnt<0>();
  asm volatile("s_barrier" ::: "memory");
  compute(s0a, s0b);
}

// ---------------- QKV fp8 GEMM (h8 x w8): q8, k8, vt8 -----------------------
// 128x128 tile, 64x64 wave tile -> grid (64, 4, 3) = 768 blocks. K=512.
__global__ __launch_bounds__(256) void gemm_qkv(const uint8_t* __restrict__ h8,
                                                const uint8_t* __restrict__ w8,
                                                const float* __restrict__ bq,
                                                const float* __restrict__ bk,
                                                const float* __restrict__ bv,
                                                uint8_t* __restrict__ q8,
                                                uint8_t* __restrict__ k8,
                                                uint8_t* __restrict__ vt8) {
  int z = blockIdx.z;
  int m0 = blockIdx.x * 128, n0 = blockIdx.y * 128;
  floatx4 acc[4][4];
  floatx4 accl[4];
  gemm_fp8<128, 128, 4, 4, 256, false>(h8 + (size_t)m0 * C_, C_,
                                       w8 + (size_t)z * C_ * C_ + (size_t)n0 * C_,
                                       C_, C_, acc, accl);
  int tid = threadIdx.x, w = tid >> 6, lane = tid & 63;
  int wrow = w >> 1, wcol = w & 1;           // WCOLS=2
  int col = lane & 15, quad = lane >> 4;
  const float* bias = (z == 0) ? bq : (z == 1) ? bk : bv;
  if (z < 2) {
    uint8_t* out = (z == 0) ? q8 : k8;
#pragma unroll
    for (int mt = 0; mt < 4; mt++)
#pragma unroll
      for (int nt = 0; nt < 4; nt++) {
        int n = n0 + wcol * 64 + nt * 16 + col;
        float bb = bias[n];
#pragma unroll
        for (int r = 0; r < 4; r++) {
          int m = m0 + wrow * 64 + mt * 16 + quad * 4 + r;
          out[(size_t)m * C_ + n] = (uint8_t)f32_to_fp8(acc[mt][nt][r] + bb);
        }
      }
  } else {
    // vt8[b][c][s] = fp8(v[b*4096+s][c]); 4 consecutive s -> packed int store
#pragma unroll
    for (int mt = 0; mt < 4; mt++)
#pragma unroll
      for (int nt = 0; nt < 4; nt++) {
        int n = n0 + wcol * 64 + nt * 16 + col;
        float bb = bias[n];
        int mbase = m0 + wrow * 64 + mt * 16 + quad * 4;
        int b = mbase >> 12;
        int s = mbase & 4095;
        int pk = pack4_fp8(acc[mt][nt][0] + bb, acc[mt][nt][1] + bb,
                           acc[mt][nt][2] + bb, acc[mt][nt][3] + bb);
        *reinterpret_cast<int*>(vt8 + ((size_t)b * C_ + n) * HW_ + s) = pk;
      }
  }
}

// ---------------- QK^T fp8 GEMM -> P8 = fp8(exp(S*scale)) -------------------
// R25: 128x128 dbuf (2 blocks/CU, counted vmcnt) + R17 XCD swizzle, no
// rowsum. grid (32, 32, B): each XCD gets all 32 m-panels x 4 n-panels
// (q8 2MB L2-resident per XCD). K=512 -> 4 iters.
__global__ __launch_bounds__(256) void gemm_qk(const uint8_t* __restrict__ q8,
                                               const uint8_t* __restrict__ k8,
                                               uint8_t* __restrict__ P8) {
  int b = blockIdx.z;
  int fid = blockIdx.y * 32 + blockIdx.x;    // 0..1023
  int nid = (fid & 7) * 128 + (fid >> 3);    // XCD-contiguous chunks of 128
  int m0 = (nid & 31) * 128, n0 = (nid >> 5) * 128;
  floatx4 acc[4][4];
  floatx4 accl[4];
  gemm_fp8<128, 128, 4, 4, 256, false>(q8 + ((size_t)b * HW_ + m0) * C_, C_,
                                       k8 + ((size_t)b * HW_ + n0) * C_, C_,
                                       C_, acc, accl);
  int tid = threadIdx.x, w = tid >> 6, lane = tid & 63;
  int wrow = w >> 1, wcol = w & 1;           // WCOLS=2
  int col = lane & 15, quad = lane >> 4;
  const float sl2e = 0.044194173824159216f * 1.4426950408889634f; // scale*log2e
  uint8_t* Pb = P8 + (size_t)b * HW_ * HW_;
#pragma unroll
  for (int mt = 0; mt < 4; mt++) {
#pragma unroll
    for (int nt = 0; nt < 4; nt++) {
      int n = n0 + wcol * 64 + nt * 16 + col;
      float p0 = exp2f(acc[mt][nt][0] * sl2e);
      float p1 = exp2f(acc[mt][nt][1] * sl2e);
      float p2 = exp2f(acc[mt][nt][2] * sl2e);
      float p3 = exp2f(acc[mt][nt][3] * sl2e);
      int pk = pack4_fp8(p0, p1, p2, p3);
      size_t base = (size_t)(m0 + wrow * 64 + mt * 16 + quad * 4) * HW_ + n;
      Pb[base]           = (uint8_t)pk;
      Pb[base + HW_]     = (uint8_t)((unsigned)pk >> 8);
      Pb[base + 2 * HW_] = (uint8_t)((unsigned)pk >> 16);
      Pb[base + 3 * HW_] = (uint8_t)((unsigned)pk >> 24);
    }
  }
}

// ---------------- PV fp8 GEMM: O = P8 * V8^T, l = P8 x 1, o = O/l -----------
// 128x64 tile, dbuf -> grid (32, 8, B) = 512 blocks (2/CU). K=4096 -> 32
// iters. XCD swizzle: XCD x owns 4 P8 m-panels x all 8 n-tiles -> P8 (2MB)
// + vt8 (2MB) L2-resident. l via ones-MFMA: accl[mt][r] lands on exactly
// the lane that writes row m = m0+w*32+mt*16+quad*4+r.
__global__ __launch_bounds__(256) void gemm_pv(const uint8_t* __restrict__ P8,
                                               const uint8_t* __restrict__ vt8,
                                               bf16* __restrict__ o) {
  int b = blockIdx.z;
  int fid = blockIdx.y * 32 + blockIdx.x;    // 0..255
  int xcd = fid & 7, i = fid >> 3;           // i in 0..31
  int m0 = (xcd * 4 + (i & 3)) * 128;        // 4 m-panels per XCD
  int n0 = (i >> 2) * 64;                    // all 8 n-tiles per XCD
  floatx4 acc[2][4];
  floatx4 accl[2];
  gemm_fp8<128, 64, 2, 4, 256, true>(P8 + (size_t)b * HW_ * HW_ + (size_t)m0 * HW_,
                                     HW_, vt8 + ((size_t)b * C_ + n0) * HW_, HW_,
                                     HW_, acc, accl);
  int tid = threadIdx.x, w = tid >> 6, lane = tid & 63;
  int col = lane & 15, quad = lane >> 4;     // WCOLS=1 -> wave rows w*32
  bf16* ob = o + (size_t)b * HW_ * C_;
#pragma unroll
  for (int mt = 0; mt < 2; mt++)
#pragma unroll
    for (int r = 0; r < 4; r++) {
      int m = m0 + w * 32 + mt * 16 + quad * 4 + r;
      float inv = 1.0f / accl[mt][r];
#pragma unroll
      for (int nt = 0; nt < 4; nt++) {
        int n = n0 + nt * 16 + col;
        ob[(size_t)m * C_ + n] = (bf16)(acc[mt][nt][r] * inv);
      }
    }
}

// ---------------- Proj GEMM + residual: out = x + o*wp + bp (fp32) ----------
// 128x64 tile, dbuf (R17 config) -> grid (64, 8) = 512 blocks (2/CU).
__global__ __launch_bounds__(256) void gemm_proj(const bf16* __restrict__ o,
                                                 const bf16* __restrict__ wtp,
                                                 const float* __restrict__ bp,
                                                 const float* __restrict__ x,
                                                 float* __restrict__ out) {
  int m0 = blockIdx.x * 128, n0 = blockIdx.y * 64;
  floatx4 acc[2][4];
  gemm_main<128, 64, 2, 4>(o + (size_t)m0 * C_, C_, wtp + (size_t)n0 * C_, C_, C_, acc);
  int tid = threadIdx.x, w = tid >> 6, lane = tid & 63;
  int col = lane & 15, quad = lane >> 4;     // WCOLS=1 -> wave rows w*32
#pragma unroll
  for (int mt = 0; mt < 2; mt++)
#pragma unroll
    for (int nt = 0; nt < 4; nt++) {
      int n = n0 + nt * 16 + col;
      float bb = bp[n];
#pragma unroll
      for (int r = 0; r < 4; r++) {
        int m = m0 + w * 32 + mt * 16 + quad * 4 + r;
        out[(size_t)m * C_ + n] = x[(size_t)m * C_ + n] + acc[mt][nt][r] + bb;
      }
    }
}

// ---------------- launch -----------------------------------------------------
extern "C" void kernel_launch(void* const* d_in, const int* in_sizes, int n_in,
                              void* d_out, int out_size, void* d_ws, size_t ws_size,
                              hipStream_t stream) {
  const float* x     = (const float*)d_in[0];
  const float* gamma = (const float*)d_in[1];
  const float* beta  = (const float*)d_in[2];
  const float* wq    = (const float*)d_in[3];
  const float* bq    = (const float*)d_in[4];
  const float* wk    = (const float*)d_in[5];
  const float* bk    = (const float*)d_in[6];
  const float* wv    = (const float*)d_in[7];
  const float* bv    = (const float*)d_in[8];
  const float* wp    = (const float*)d_in[9];
  const float* bp    = (const float*)d_in[10];
  float* out = (float*)d_out;

  char* w8s = (char*)d_ws;
  float* stats = (float*)(w8s);                      // 512 B
  float* pp    = (float*)(w8s + 393216u);            // 128 KB
  uint8_t* w8  = (uint8_t*)(w8s + (1u << 20));       // 768 KB (fp8 wq/wk/wv ^T)
  bf16* wtp    = (bf16*)(w8s + (2u << 20));          // 512 KB (bf16 wp^T)
  uint8_t* h8  = (uint8_t*)(w8s + (4u << 20));       // 4 MB
  bf16* o      = (bf16*)(w8s + (8u << 20));          // 8 MB
  uint8_t* q8  = (uint8_t*)(w8s + (16u << 20));      // 4 MB
  uint8_t* k8  = (uint8_t*)(w8s + (20u << 20));      // 4 MB
  uint8_t* vt8 = (uint8_t*)(w8s + (24u << 20));      // 4 MB
  uint8_t* P8  = (uint8_t*)(w8s + (28u << 20));      // 32 MB -> 60 MB total

  gn_part<<<512, 256, 0, stream>>>(x, pp);
  finish_wtrans<<<1088, 256, 0, stream>>>(pp, stats, wq, wk, wv, wp, w8, wtp);
  gn_apply<<<4096, 256, 0, stream>>>(x, gamma, beta, stats, h8);
  gemm_qkv<<<dim3(M_ / 128, C_ / 128, 3), 256, 0, stream>>>(h8, w8, bq, bk, bv, q8, k8, vt8);
  gemm_qk<<<dim3(HW_ / 128, HW_ / 128, B_), 256, 0, stream>>>(q8, k8, P8);
  gemm_pv<<<dim3(HW_ / 128, C_ / 64, B_), 256, 0, stream>>>(P8, vt8, o);
  gemm_proj<<<dim3(M_ / 128, C_ / 64, 1), 256, 0, stream>>>(o, wtp, bp, x, out);
}